// Round 2
// baseline (42.719 us; speedup 1.0000x reference)
//
#include <hip/hip_runtime.h>
#include <math.h>

// ---------------------------------------------------------------------------
// QuantumPureQCNN: 16-qubit statevector, B=32.
// qubit q <-> bit (15-q) of the state index.
//
// Decomposition:
//   amp_init(t) = 2^-8 * chain over 16 sites (bond-dim-2 exact contraction)
//   post-init circuit = V0 (bits15..12) ⊗ V1 (11..8) ⊗ V2 (7..4) ⊗ V3 (3..0)
//     where V_n = G2_(b3,b1) * (G1a_(b3,b2) ⊗ G1b_(b1,b0)),
//     G = (RY⊗I)*CNOT*ZZ*YY*XX  (4x4, batch-independent).
//   outputs: Z on bits 15,11,7,3; V0 commutes with bit-11/7/3 marginals.
// ---------------------------------------------------------------------------

struct C { float x, y; };
__device__ __forceinline__ C operator+(C a, C b){ return {a.x+b.x, a.y+b.y}; }
__device__ __forceinline__ C operator-(C a, C b){ return {a.x-b.x, a.y-b.y}; }
__device__ __forceinline__ C cmul(C a, C b){ return { a.x*b.x - a.y*b.y, a.x*b.y + a.y*b.x }; }
__device__ __forceinline__ C cfma(C a, C b, C acc){
  acc.x = fmaf(a.x, b.x, fmaf(-a.y, b.y, acc.x));
  acc.y = fmaf(a.x, b.y, fmaf( a.y, b.x, acc.y));
  return acc;
}
__device__ __forceinline__ C cscale(C a, float s){ return {a.x*s, a.y*s}; }

// ws layout in C (8B) units:
//   Uw    : [32][16][4]      ->   0 .. 2047   (per-batch single-qubit mats)
//   Vw    : [4][16][16]      -> 2048 .. 3071  (nibble unitaries, row-major)
//   qpart : 2048 floats      -> 3072 .. 4095  ([b][chunk][4] block partials)
//   state : [32][65536]      -> 4096 .. 4096+2097151
#define WS_U     0
#define WS_V     2048
#define WS_QPART 3072
#define WS_STATE 4096

// -------------------------------- K0: setup --------------------------------
__global__ void qk_setup(const float* __restrict__ x, const float* __restrict__ w,
                         C* __restrict__ Uw, C* __restrict__ Vw)
{
  __shared__ C G[12][16];
  int tid = threadIdx.x;

  if (tid < 12) {
    // pairs 0..7: block-1 (qubits 2p,2p+1); 8..11: block-2 (qubits 4n,4n+2)
    float a0, a1, a2, ry;
    if (tid < 8) { a0 = w[3*tid];   a1 = w[3*tid+1];  a2 = w[3*tid+2];  ry = w[24+tid]; }
    else { int n = tid-8; a0 = w[32+3*n]; a1 = w[33+3*n]; a2 = w[34+3*n]; ry = w[44+n]; }

    C M[16], T[16];
    // XX
    float c0 = cosf(0.5f*a0), s0 = sinf(0.5f*a0);
    for (int i=0;i<16;i++) M[i] = {0.f,0.f};
    M[0]={c0,0}; M[5]={c0,0}; M[10]={c0,0}; M[15]={c0,0};
    M[3]={0,-s0}; M[6]={0,-s0}; M[9]={0,-s0}; M[12]={0,-s0};
    // YY * M
    float c1 = cosf(0.5f*a1), s1 = sinf(0.5f*a1);
    C Y[16];
    for (int i=0;i<16;i++) Y[i] = {0.f,0.f};
    Y[0]={c1,0}; Y[5]={c1,0}; Y[10]={c1,0}; Y[15]={c1,0};
    Y[3]={0,s1}; Y[12]={0,s1}; Y[6]={0,-s1}; Y[9]={0,-s1};
    for (int r=0;r<4;r++) for (int c=0;c<4;c++){
      C acc{0,0};
      for (int k=0;k<4;k++) acc = cfma(Y[r*4+k], M[k*4+c], acc);
      T[r*4+c] = acc;
    }
    // ZZ * T  (diag(em,ep,ep,em))
    float c2 = cosf(0.5f*a2), s2 = sinf(0.5f*a2);
    C em = {c2,-s2}, ep = {c2,s2};
    for (int c=0;c<4;c++){
      M[0*4+c] = cmul(em, T[0*4+c]);
      M[1*4+c] = cmul(ep, T[1*4+c]);
      M[2*4+c] = cmul(ep, T[2*4+c]);
      M[3*4+c] = cmul(em, T[3*4+c]);
    }
    // CNOT * M : swap rows 2,3
    for (int c=0;c<4;c++){
      T[0*4+c] = M[0*4+c]; T[1*4+c] = M[1*4+c];
      T[2*4+c] = M[3*4+c]; T[3*4+c] = M[2*4+c];
    }
    // (RY ⊗ I) * T
    float cr = cosf(0.5f*ry), sr = sinf(0.5f*ry);
    for (int c=0;c<4;c++){
      C r0=T[0*4+c], r1=T[1*4+c], r2=T[2*4+c], r3=T[3*4+c];
      G[tid][0*4+c] = cscale(r0,cr) - cscale(r2,sr);
      G[tid][1*4+c] = cscale(r1,cr) - cscale(r3,sr);
      G[tid][2*4+c] = cscale(r0,sr) + cscale(r2,cr);
      G[tid][3*4+c] = cscale(r1,sr) + cscale(r3,cr);
    }
  }
  __syncthreads();

  // V_n[lp,lc] = sum_{m3,m1} G2[(p3,p1),(m3,m1)] * G1a[(m3,p2),(l3,l2)] * G1b[(m1,p0),(l1,l0)]
  {
    int lp = tid >> 4, lc = tid & 15;
    int p3=(lp>>3)&1, p2=(lp>>2)&1, p1=(lp>>1)&1, p0=lp&1;
    int l3=(lc>>3)&1, l2=(lc>>2)&1, l1=(lc>>1)&1, l0=lc&1;
    for (int n=0;n<4;n++){
      C acc{0,0};
      #pragma unroll
      for (int m3=0;m3<2;m3++)
      #pragma unroll
      for (int m1=0;m1<2;m1++){
        C g2 = G[8+n]  [(p3*2+p1)*4 + (m3*2+m1)];
        C ga = G[2*n]  [(m3*2+p2)*4 + (l3*2+l2)];
        C gb = G[2*n+1][(m1*2+p0)*4 + (l1*2+l0)];
        acc = cfma(g2, cmul(ga, gb), acc);
      }
      Vw[n*256 + lp*16 + lc] = acc;
    }
  }

  // per-(batch,qubit) single-qubit U = RZ*RY*RX, angle x[b,q]
  for (int idx = tid; idx < 512; idx += 256){
    int b = idx >> 4, q = idx & 15;
    float h = 0.5f * x[b*16 + q];
    float c = cosf(h), s = sinf(h);
    C em = {c,-s}, ep = {c,s};
    C A00 = { c*c,  s*s}, A01 = {-c*s, -c*s};
    C A10 = { c*s, -c*s}, A11 = { c*c, -s*s};
    Uw[idx*4+0] = cmul(em, A00);
    Uw[idx*4+1] = cmul(em, A01);
    Uw[idx*4+2] = cmul(ep, A10);
    Uw[idx*4+3] = cmul(ep, A11);
  }
}

// ----------------------- K1: init chain + V3,V2,V1 --------------------------
#define SPAD(i) ((i) + ((i) >> 4))   // pad: i + i/16, injective, spreads banks

__global__ __launch_bounds__(256) void qk_state(const C* __restrict__ Uw,
                                                const C* __restrict__ Vw,
                                                C* __restrict__ state)
{
  __shared__ C sAmp[4352];   // 4096 amps + pad
  __shared__ C vL[768];      // V1,V2,V3
  __shared__ C uL[64];       // 16 single-qubit 2x2 mats for this batch
  int tid = threadIdx.x;
  int b = blockIdx.x >> 4, ch = blockIdx.x & 15;   // ch = bits 15..12 of t

  for (int i = tid; i < 768; i += 256) vL[i] = Vw[256 + i];
  if (tid < 64) uL[tid] = Uw[b*64 + tid];
  __syncthreads();

  // bond-dim-2 chain: prefix over qubits 0..11 (t bits 15..4 = ch,tid)
  C f0, f1;
  {
    int t0 = (ch >> 3) & 1;
    C a = uL[t0*2+0], bb = uL[t0*2+1];
    f0 = a + bb; f1 = a - bb;
  }
  #pragma unroll
  for (int q = 1; q < 12; q++){
    int tq = (q < 4) ? ((ch >> (3-q)) & 1) : ((tid >> (11-q)) & 1);
    C a  = cmul(f0, uL[q*4 + tq*2 + 0]);
    C bb = cmul(f1, uL[q*4 + tq*2 + 1]);
    f0 = a + bb; f1 = a - bb;
  }
  const float inv = 1.0f / 256.0f;   // 2^-8 from H^16
  #pragma unroll
  for (int j = 0; j < 16; j++){      // t bits 3..0 = qubits 12..15
    C g0 = f0, g1 = f1;
    #pragma unroll
    for (int q = 12; q < 15; q++){
      int tq = (j >> (15-q)) & 1;
      C a  = cmul(g0, uL[q*4 + tq*2 + 0]);
      C bb = cmul(g1, uL[q*4 + tq*2 + 1]);
      g0 = a + bb; g1 = a - bb;
    }
    int t15 = j & 1;
    C amp = cmul(g0, uL[60 + t15*2 + 0]) + cmul(g1, uL[60 + t15*2 + 1]);
    sAmp[SPAD(tid*16 + j)] = cscale(amp, inv);
  }
  __syncthreads();

  C in[16], out[16];

  // V3 on bits 3..0 (stride 1), vL offset 512
  {
    int base = tid * 16;
    #pragma unroll
    for (int k=0;k<16;k++) in[k] = sAmp[SPAD(base + k)];
    #pragma unroll
    for (int r=0;r<16;r++){
      C acc{0,0};
      #pragma unroll
      for (int k=0;k<16;k++) acc = cfma(vL[512 + r*16 + k], in[k], acc);
      out[r] = acc;
    }
    #pragma unroll
    for (int r=0;r<16;r++) sAmp[SPAD(base + r)] = out[r];
  }
  __syncthreads();

  // V2 on bits 7..4 (stride 16), vL offset 256
  {
    int base = (tid >> 4)*256 + (tid & 15);
    #pragma unroll
    for (int k=0;k<16;k++) in[k] = sAmp[SPAD(base + k*16)];
    #pragma unroll
    for (int r=0;r<16;r++){
      C acc{0,0};
      #pragma unroll
      for (int k=0;k<16;k++) acc = cfma(vL[256 + r*16 + k], in[k], acc);
      out[r] = acc;
    }
    #pragma unroll
    for (int r=0;r<16;r++) sAmp[SPAD(base + r*16)] = out[r];
  }
  __syncthreads();

  // V1 on bits 11..8 (stride 256), vL offset 0; write result straight to global
  {
    #pragma unroll
    for (int k=0;k<16;k++) in[k] = sAmp[SPAD(tid + k*256)];
    #pragma unroll
    for (int r=0;r<16;r++){
      C acc{0,0};
      #pragma unroll
      for (int k=0;k<16;k++) acc = cfma(vL[r*16 + k], in[k], acc);
      out[r] = acc;
    }
    C* sp = state + b*65536 + ch*4096 + tid;
    #pragma unroll
    for (int r=0;r<16;r++) sp[r*256] = out[r];   // coalesced
  }
}

// --------------------- K2: V0 (bits 15..12) + measurement -------------------
__global__ __launch_bounds__(256) void qk_measure(const C* __restrict__ Vw,
                                                  const C* __restrict__ state,
                                                  float* __restrict__ qpart)
{
  __shared__ C v0[256];
  __shared__ float red[4][4];
  int tid = threadIdx.x;
  int b = blockIdx.x >> 4, cc = blockIdx.x & 15;
  v0[tid] = Vw[tid];
  __syncthreads();

  int j = cc*256 + tid;                       // column = bits 11..0
  const C* sp = state + b*65536 + j;
  C a[16];
  #pragma unroll
  for (int i=0;i<16;i++) a[i] = sp[i*4096];   // coalesced per i

  float sall = 0.f, sz = 0.f;
  #pragma unroll
  for (int r=0;r<16;r++){
    C acc{0,0};
    #pragma unroll
    for (int k=0;k<16;k++) acc = cfma(v0[r*16 + k], a[k], acc);
    float p = fmaf(acc.x, acc.x, acc.y*acc.y);
    sall += p;
    sz += (r & 8) ? -p : p;                   // Z on bit 15 (bit3 of r)
  }
  float s1 = ((j>>11)&1) ? -sall : sall;      // Z on bit 11 (qubit 4)
  float s2 = ((j>> 7)&1) ? -sall : sall;      // Z on bit 7  (qubit 8)
  float s3 = ((j>> 3)&1) ? -sall : sall;      // Z on bit 3  (qubit 12)

  #pragma unroll
  for (int off = 32; off > 0; off >>= 1){
    sz += __shfl_down(sz, off);
    s1 += __shfl_down(s1, off);
    s2 += __shfl_down(s2, off);
    s3 += __shfl_down(s3, off);
  }
  int wv = tid >> 6;
  if ((tid & 63) == 0){ red[wv][0]=sz; red[wv][1]=s1; red[wv][2]=s2; red[wv][3]=s3; }
  __syncthreads();
  if (tid == 0){
    float r0=0,r1=0,r2=0,r3=0;
    for (int w2=0; w2<4; w2++){ r0+=red[w2][0]; r1+=red[w2][1]; r2+=red[w2][2]; r3+=red[w2][3]; }
    int o = (b*16 + cc)*4;
    qpart[o+0]=r0; qpart[o+1]=r1; qpart[o+2]=r2; qpart[o+3]=r3;   // deterministic
  }
}

// ------------------------------ K3: final matmul ----------------------------
__global__ void qk_out(const float* __restrict__ qpart, const float* __restrict__ Wm,
                       const float* __restrict__ bias, float* __restrict__ outp)
{
  int tid = threadIdx.x;
  if (tid >= 288) return;
  int bb = tid / 9, o = tid % 9;
  float q[4] = {0,0,0,0};
  for (int cc=0; cc<16; cc++){
    int base = (bb*16 + cc)*4;
    q[0] += qpart[base+0]; q[1] += qpart[base+1];
    q[2] += qpart[base+2]; q[3] += qpart[base+3];
  }
  float acc = bias[o];
  #pragma unroll
  for (int k=0;k<4;k++) acc = fmaf(q[k], Wm[o*4+k], acc);
  outp[bb*9 + o] = acc;
}

// -----------------------------------------------------------------------------
extern "C" void kernel_launch(void* const* d_in, const int* in_sizes, int n_in,
                              void* d_out, int out_size, void* d_ws, size_t ws_size,
                              hipStream_t stream)
{
  (void)in_sizes; (void)n_in; (void)out_size; (void)ws_size;
  const float* x    = (const float*)d_in[0];   // [32][16]
  const float* w    = (const float*)d_in[1];   // [78]
  const float* Wm   = (const float*)d_in[2];   // [9][4]
  const float* bias = (const float*)d_in[3];   // [9]
  float* outp = (float*)d_out;                 // [32][9]

  C* ws = (C*)d_ws;
  C* Uw       = ws + WS_U;
  C* Vw       = ws + WS_V;
  float* qpart= (float*)(ws + WS_QPART);
  C* state    = ws + WS_STATE;                 // 32*65536 C = 16 MB

  qk_setup  <<<  1, 256, 0, stream>>>(x, w, Uw, Vw);
  qk_state  <<<512, 256, 0, stream>>>(Uw, Vw, state);
  qk_measure<<<512, 256, 0, stream>>>(Vw, state, qpart);
  qk_out    <<<  1, 320, 0, stream>>>(qpart, Wm, bias, outp);
}

// Round 3
// 10.486 us; speedup vs baseline: 4.0739x; 4.0739x over previous
//
#include <hip/hip_runtime.h>
#include <math.h>

// ---------------------------------------------------------------------------
// QuantumPureQCNN, fully collapsed to a bond-2 MPS transfer-matrix contraction.
//
// qubit q <-> state bit (15-q).  After H^16 + CZ-chain + per-qubit RZ*RY*RX:
//   psi(t) = 2^-8 * u . A_0(t0) A_1(t1) ... A_14(t14) . c(t15),   u=[1,1]
//   A_q(t) = [[U_q[t,0], U_q[t,0]], [U_q[t,1], -U_q[t,1]]]  (2x2, bond dim 2)
//   c(t)   = [U_15[t,0], U_15[t,1]]^T
// The QCNN circuit = V0 x V1 x V2 x V3 on the 4 nibbles (qubits 4n..4n+3),
//   V_n = G2_(b3,b1) * (G1a_(b3,b2) x G1b_(b1,b0)),  G = RY*CNOT*ZZ*YY*XX.
// Each V_n acts on 4 adjacent MPS sites -> boundary bonds stay dim 2:
//   M_n(s)[a,b] = sum_{s'} V_n[s,s'] * (A_{4n}..A_{4n+3})(s')[a,b]
// Measurements (Z on each nibble's bit3) via doubled 4x4 transfer matrices:
//   D_n^w[(aa'),(bb')] = sum_s w(s) M_n(s)[a,b] conj(M_n(s)[a',b'])
//   E_o = [1,1,1,1] . D_0^{w0} D_1^{w1} D_2^{w2} . (D_3^{w3} col (0,0)) / 65536
// One kernel, one block per batch (32 x 256), ~15 KB LDS, no workspace.
// ---------------------------------------------------------------------------

struct C { float x, y; };
__device__ __forceinline__ C operator+(C a, C b){ return {a.x+b.x, a.y+b.y}; }
__device__ __forceinline__ C operator-(C a, C b){ return {a.x-b.x, a.y-b.y}; }
__device__ __forceinline__ C cmul(C a, C b){ return { a.x*b.x - a.y*b.y, a.x*b.y + a.y*b.x }; }
__device__ __forceinline__ C cfma(C a, C b, C acc){
  acc.x = fmaf(a.x, b.x, fmaf(-a.y, b.y, acc.x));
  acc.y = fmaf(a.x, b.y, fmaf( a.y, b.x, acc.y));
  return acc;
}
// acc += a * conj(b)
__device__ __forceinline__ C cfmac(C a, C b, C acc){
  acc.x = fmaf(a.x, b.x, fmaf( a.y, b.y, acc.x));
  acc.y = fmaf(a.y, b.x, fmaf(-a.x, b.y, acc.y));
  return acc;
}
__device__ __forceinline__ C cscale(C a, float s){ return {a.x*s, a.y*s}; }

__global__ __launch_bounds__(256) void qk_all(const float* __restrict__ x,
                                              const float* __restrict__ w,
                                              const float* __restrict__ Wm,
                                              const float* __restrict__ bias,
                                              float* __restrict__ outp)
{
  __shared__ C G[12][16];     // fused pair gates
  __shared__ C uL[64];        // 16 single-qubit 2x2 (RZ*RY*RX)
  __shared__ C sV[1024];      // V_n [4][16][16]
  __shared__ C sT[256];       // site products [4][16][2][2]
  __shared__ C sM[256];       // M_n [4][16][2][2]
  __shared__ C sDp[64];       // D_n^+ [4][16]
  __shared__ C sDz[64];       // D_n^Z [4][16]
  __shared__ float qv[4];

  const int tid = threadIdx.x;
  const int b   = blockIdx.x;

  // ---------------- Phase A: pair gates G (lanes 0..11) + U mats (64..79) ---
  if (tid < 12) {
    float a0, a1, a2, ry;
    if (tid < 8) { a0 = w[3*tid];   a1 = w[3*tid+1];  a2 = w[3*tid+2];  ry = w[24+tid]; }
    else { int n = tid-8; a0 = w[32+3*n]; a1 = w[33+3*n]; a2 = w[34+3*n]; ry = w[44+n]; }

    C M[16], T[16];
    float c0 = cosf(0.5f*a0), s0 = sinf(0.5f*a0);
    for (int i=0;i<16;i++) M[i] = {0.f,0.f};
    M[0]={c0,0}; M[5]={c0,0}; M[10]={c0,0}; M[15]={c0,0};
    M[3]={0,-s0}; M[6]={0,-s0}; M[9]={0,-s0}; M[12]={0,-s0};
    float c1 = cosf(0.5f*a1), s1 = sinf(0.5f*a1);
    C Y[16];
    for (int i=0;i<16;i++) Y[i] = {0.f,0.f};
    Y[0]={c1,0}; Y[5]={c1,0}; Y[10]={c1,0}; Y[15]={c1,0};
    Y[3]={0,s1}; Y[12]={0,s1}; Y[6]={0,-s1}; Y[9]={0,-s1};
    for (int r=0;r<4;r++) for (int c=0;c<4;c++){
      C acc{0,0};
      for (int k=0;k<4;k++) acc = cfma(Y[r*4+k], M[k*4+c], acc);
      T[r*4+c] = acc;
    }
    float c2 = cosf(0.5f*a2), s2 = sinf(0.5f*a2);
    C em = {c2,-s2}, ep = {c2,s2};
    for (int c=0;c<4;c++){
      M[0*4+c] = cmul(em, T[0*4+c]);
      M[1*4+c] = cmul(ep, T[1*4+c]);
      M[2*4+c] = cmul(ep, T[2*4+c]);
      M[3*4+c] = cmul(em, T[3*4+c]);
    }
    for (int c=0;c<4;c++){        // CNOT: swap rows 2,3
      T[0*4+c] = M[0*4+c]; T[1*4+c] = M[1*4+c];
      T[2*4+c] = M[3*4+c]; T[3*4+c] = M[2*4+c];
    }
    float cr = cosf(0.5f*ry), sr = sinf(0.5f*ry);
    for (int c=0;c<4;c++){        // (RY x I)
      C r0=T[0*4+c], r1=T[1*4+c], r2=T[2*4+c], r3=T[3*4+c];
      G[tid][0*4+c] = cscale(r0,cr) - cscale(r2,sr);
      G[tid][1*4+c] = cscale(r1,cr) - cscale(r3,sr);
      G[tid][2*4+c] = cscale(r0,sr) + cscale(r2,cr);
      G[tid][3*4+c] = cscale(r1,sr) + cscale(r3,cr);
    }
  }
  if (tid >= 64 && tid < 80) {    // wave 1: U_q = RZ*RY*RX, angle x[b,q]
    int q = tid - 64;
    float h = 0.5f * x[b*16 + q];
    float c = cosf(h), s = sinf(h);
    C em = {c,-s}, ep = {c,s};
    C A00 = { c*c,  s*s}, A01 = {-c*s, -c*s};
    C A10 = { c*s, -c*s}, A11 = { c*c, -s*s};
    uL[q*4+0] = cmul(em, A00);
    uL[q*4+1] = cmul(em, A01);
    uL[q*4+2] = cmul(ep, A10);
    uL[q*4+3] = cmul(ep, A11);
  }
  __syncthreads();

  // ---------------- Phase B: assemble V_n (all 256) + site chains (0..63) ---
  {
    int lp = tid >> 4, lc = tid & 15;
    int p3=(lp>>3)&1, p2=(lp>>2)&1, p1=(lp>>1)&1, p0=lp&1;
    int l3=(lc>>3)&1, l2=(lc>>2)&1, l1=(lc>>1)&1, l0=lc&1;
    for (int n=0;n<4;n++){
      C acc{0,0};
      #pragma unroll
      for (int m3=0;m3<2;m3++)
      #pragma unroll
      for (int m1=0;m1<2;m1++){
        C g2 = G[8+n]  [(p3*2+p1)*4 + (m3*2+m1)];
        C ga = G[2*n]  [(m3*2+p2)*4 + (l3*2+l2)];
        C gb = G[2*n+1][(m1*2+p0)*4 + (l1*2+l0)];
        acc = cfma(g2, cmul(ga, gb), acc);
      }
      sV[n*256 + lp*16 + lc] = acc;
    }
  }
  if (tid < 64) {                 // T_n(s) = A_{4n}(t0) A(t1) A(t2) A/Chat(t3)
    int n = tid >> 4, s = tid & 15;
    int t0 = (s>>3)&1;
    C u0 = uL[(4*n)*4 + t0*2 + 0], u1 = uL[(4*n)*4 + t0*2 + 1];
    C P00=u0, P01=u0, P10=u1, P11={-u1.x,-u1.y};
    #pragma unroll
    for (int i=1;i<4;i++){
      int t = (s >> (3-i)) & 1;
      int q = 4*n + i;
      C v0 = uL[q*4 + t*2 + 0], v1 = uL[q*4 + t*2 + 1];
      C b00, b01, b10, b11;
      if (n == 3 && i == 3) { b00=v0; b01={0,0}; b10=v1; b11={0,0}; }   // Chat
      else { b00=v0; b01=v0; b10=v1; b11={-v1.x,-v1.y}; }               // A-form
      C n00 = cfma(P01, b10, cmul(P00, b00));
      C n01 = cfma(P01, b11, cmul(P00, b01));
      C n10 = cfma(P11, b10, cmul(P10, b00));
      C n11 = cfma(P11, b11, cmul(P10, b01));
      P00=n00; P01=n01; P10=n10; P11=n11;
    }
    int base = tid << 2;          // [n][s][a][b]
    sT[base+0]=P00; sT[base+1]=P01; sT[base+2]=P10; sT[base+3]=P11;
  }
  __syncthreads();

  // ---------------- Phase C: M_n(s)[a,b] = sum_{s'} V_n[s,s'] T_n(s')[a,b] --
  {
    int n = tid >> 6, s = (tid >> 2) & 15, ab = tid & 3;
    const C* vr = &sV[n*256 + s*16];
    const C* tn = &sT[(n<<6) + ab];
    C acc{0,0};
    #pragma unroll
    for (int k=0;k<16;k++) acc = cfma(vr[k], tn[k<<2], acc);
    sM[tid] = acc;
  }
  __syncthreads();

  // ---------------- Phase D: doubled transfers D_n^{+,Z} ---------------------
  if (tid < 64) {
    int n = tid >> 4, p = tid & 15;
    int a=(p>>3)&1, a2=(p>>2)&1, bb=(p>>1)&1, b2=p&1;
    const C* mn = &sM[n<<6];
    C Slo{0,0}, Shi{0,0};
    #pragma unroll
    for (int s=0;s<8;s++)  Slo = cfmac(mn[(s<<2)+(a<<1)+bb], mn[(s<<2)+(a2<<1)+b2], Slo);
    #pragma unroll
    for (int s=8;s<16;s++) Shi = cfmac(mn[(s<<2)+(a<<1)+bb], mn[(s<<2)+(a2<<1)+b2], Shi);
    sDp[tid] = Slo + Shi;
    sDz[tid] = Slo - Shi;
  }
  __syncthreads();

  // ---------------- Phase E: contract 4 outputs ------------------------------
  if (tid < 4) {
    int o = tid;
    C v0={1,0}, v1={1,0}, v2={1,0}, v3={1,0};
    #pragma unroll
    for (int n=0;n<3;n++){
      const C* D = (n==o) ? &sDz[n<<4] : &sDp[n<<4];
      C n0{0,0}, n1{0,0}, n2{0,0}, n3{0,0};
      n0 = cfma(v0, D[ 0], n0); n0 = cfma(v1, D[ 4], n0); n0 = cfma(v2, D[ 8], n0); n0 = cfma(v3, D[12], n0);
      n1 = cfma(v0, D[ 1], n1); n1 = cfma(v1, D[ 5], n1); n1 = cfma(v2, D[ 9], n1); n1 = cfma(v3, D[13], n1);
      n2 = cfma(v0, D[ 2], n2); n2 = cfma(v1, D[ 6], n2); n2 = cfma(v2, D[10], n2); n2 = cfma(v3, D[14], n2);
      n3 = cfma(v0, D[ 3], n3); n3 = cfma(v1, D[ 7], n3); n3 = cfma(v2, D[11], n3); n3 = cfma(v3, D[15], n3);
      v0=n0; v1=n1; v2=n2; v3=n3;
    }
    const C* D3 = (o==3) ? &sDz[3<<4] : &sDp[3<<4];
    C e{0,0};                       // column (b,b') = (0,0)
    e = cfma(v0, D3[ 0], e); e = cfma(v1, D3[ 4], e);
    e = cfma(v2, D3[ 8], e); e = cfma(v3, D3[12], e);
    qv[o] = e.x * (1.0f/65536.0f);
  }
  __syncthreads();

  // ---------------- Phase F: linear head ------------------------------------
  if (tid < 9) {
    float acc = bias[tid];
    #pragma unroll
    for (int k=0;k<4;k++) acc = fmaf(qv[k], Wm[tid*4+k], acc);
    outp[b*9 + tid] = acc;
  }
}

// -----------------------------------------------------------------------------
extern "C" void kernel_launch(void* const* d_in, const int* in_sizes, int n_in,
                              void* d_out, int out_size, void* d_ws, size_t ws_size,
                              hipStream_t stream)
{
  (void)in_sizes; (void)n_in; (void)out_size; (void)d_ws; (void)ws_size;
  const float* x    = (const float*)d_in[0];   // [32][16]
  const float* w    = (const float*)d_in[1];   // [78]
  const float* Wm   = (const float*)d_in[2];   // [9][4]
  const float* bias = (const float*)d_in[3];   // [9]
  float* outp = (float*)d_out;                 // [32][9]

  qk_all<<<32, 256, 0, stream>>>(x, w, Wm, bias, outp);
}

// Round 4
// 9.419 us; speedup vs baseline: 4.5352x; 1.1132x over previous
//
#include <hip/hip_runtime.h>
#include <math.h>

// ---------------------------------------------------------------------------
// QuantumPureQCNN, fully collapsed to a bond-2 MPS transfer-matrix contraction.
//
// qubit q <-> state bit (15-q).  After H^16 + CZ-chain + per-qubit RZ*RY*RX:
//   psi(t) = 2^-8 * u . A_0(t0) A_1(t1) ... A_14(t14) . c(t15),   u=[1,1]
//   A_q(t) = [[U_q[t,0], U_q[t,0]], [U_q[t,1], -U_q[t,1]]]  (2x2, bond dim 2)
//   c(t)   = [U_15[t,0], U_15[t,1]]^T
// The QCNN circuit = V0 x V1 x V2 x V3 on the 4 nibbles (qubits 4n..4n+3),
//   V_n = G2_(b3,b1) * (G1a_(b3,b2) x G1b_(b1,b0)),  G = RY*CNOT*ZZ*YY*XX.
// G in closed form (8 nonzeros):
//   YY*XX = diag(d_i) + antidiag(-i eps_i), d = c0c1 +/- s0s1 (sign +--+),
//   eps = c1s0 -/+ c0s1; after ZZ (row z_i in {em,ep,ep,em}), CNOT row-swap,
//   RY(x)I:  rows {0,2} live in cols {0,3} scaled by em, rows {1,3} in cols
//   {1,2} scaled by ep, entries = {cr,sr} combos of d and -i*eps.
// Each V_n acts on 4 adjacent MPS sites -> boundary bonds stay dim 2:
//   M_n(s)[a,b] = sum_{s'} V_n[s,s'] * (A_{4n}..A_{4n+3})(s')[a,b]
// Measurements (Z on each nibble's bit3) via doubled 4x4 transfer matrices:
//   D_n^w[(aa'),(bb')] = sum_s w(s) M_n(s)[a,b] conj(M_n(s)[a',b'])
//   E_o = [1,1,1,1] . D_0 D_1 D_2 . (D_3 col (0,0)) / 65536
// One kernel, one block per batch (32 x 256), ~15 KB LDS, no workspace.
// ---------------------------------------------------------------------------

struct C { float x, y; };
__device__ __forceinline__ C operator+(C a, C b){ return {a.x+b.x, a.y+b.y}; }
__device__ __forceinline__ C operator-(C a, C b){ return {a.x-b.x, a.y-b.y}; }
__device__ __forceinline__ C cmul(C a, C b){ return { a.x*b.x - a.y*b.y, a.x*b.y + a.y*b.x }; }
__device__ __forceinline__ C cfma(C a, C b, C acc){
  acc.x = fmaf(a.x, b.x, fmaf(-a.y, b.y, acc.x));
  acc.y = fmaf(a.x, b.y, fmaf( a.y, b.x, acc.y));
  return acc;
}
// acc += a * conj(b)
__device__ __forceinline__ C cfmac(C a, C b, C acc){
  acc.x = fmaf(a.x, b.x, fmaf( a.y, b.y, acc.x));
  acc.y = fmaf(a.y, b.x, fmaf(-a.x, b.y, acc.y));
  return acc;
}
__device__ __forceinline__ C cscale(C a, float s){ return {a.x*s, a.y*s}; }

__global__ __launch_bounds__(256) void qk_all(const float* __restrict__ x,
                                              const float* __restrict__ w,
                                              const float* __restrict__ Wm,
                                              const float* __restrict__ bias,
                                              float* __restrict__ outp)
{
  __shared__ C G[12][16];     // fused pair gates (sparse: 8 nonzeros each)
  __shared__ C uL[64];        // 16 single-qubit 2x2 (RZ*RY*RX)
  __shared__ C sV[1024];      // V_n [4][16][16]
  __shared__ C sT[256];       // site products [4][16][2][2]
  __shared__ C sM[256];       // M_n [4][16][2][2]
  __shared__ C sDp[64];       // D_n^+ [4][16]
  __shared__ C sDz[64];       // D_n^Z [4][16]
  __shared__ float qv[4];

  const int tid = threadIdx.x;
  const int b   = blockIdx.x;

  // ------- Phase A: one lane per (pair, element) for G; wave 3 does U -------
  {
    int p = tid >> 4;                     // pair 0..15 (12..15 unused for G)
    if (p < 12) {
      int idx = tid & 15, r = idx >> 2, c = idx & 3;
      float a0, a1, a2, ry;
      if (p < 8) { a0 = w[3*p];   a1 = w[3*p+1];  a2 = w[3*p+2];  ry = w[24+p]; }
      else { int n = p-8; a0 = w[32+3*n]; a1 = w[33+3*n]; a2 = w[34+3*n]; ry = w[44+n]; }
      float s0,c0,s1,c1,s2,c2,sr,cr;
      sincosf(0.5f*a0, &s0, &c0);
      sincosf(0.5f*a1, &s1, &c1);
      sincosf(0.5f*a2, &s2, &c2);
      sincosf(0.5f*ry, &sr, &cr);
      int rlo = r & 1, rhi = r >> 1;
      float d   = rlo ? fmaf(-s0, s1, c0*c1) : fmaf(s0, s1, c0*c1);
      float eps = rlo ? fmaf( c0, s1, c1*s0) : fmaf(-c0, s1, c1*s0);
      bool valid = rlo ? (c == 1 || c == 2) : (c == 0 || c == 3);
      bool sel   = rlo ? (c == 2) : (c == 3);   // first(diag-type) vs second
      float re, im;
      if (!sel) { re = rhi ?  sr*d : cr*d;  im = rhi ? -cr*eps :  sr*eps; }
      else      { re = rhi ?  cr*d : -sr*d; im = rhi ? -sr*eps : -cr*eps; }
      float zi = rlo ? s2 : -s2;                // z = (c2, +/- s2)
      C val;
      if (valid) val = { fmaf(re, c2, -im*zi), fmaf(re, zi, im*c2) };
      else       val = {0.f, 0.f};
      G[p][idx] = val;
    } else if (tid >= 192 && tid < 208) {       // wave 3: U_q = RZ*RY*RX
      int q = tid - 192;
      float h = 0.5f * x[b*16 + q];
      float s, c;
      sincosf(h, &s, &c);
      C em = {c,-s}, ep = {c,s};
      C A00 = { c*c,  s*s}, A01 = {-c*s, -c*s};
      C A10 = { c*s, -c*s}, A11 = { c*c, -s*s};
      uL[q*4+0] = cmul(em, A00);
      uL[q*4+1] = cmul(em, A01);
      uL[q*4+2] = cmul(ep, A10);
      uL[q*4+3] = cmul(ep, A11);
    }
  }
  __syncthreads();

  // ------- Phase B: assemble V_n (all 256) + site chains (lanes 0..63) ------
  {
    int lp = tid >> 4, lc = tid & 15;
    int p3=(lp>>3)&1, p2=(lp>>2)&1, p1=(lp>>1)&1, p0=lp&1;
    int l3=(lc>>3)&1, l2=(lc>>2)&1, l1=(lc>>1)&1, l0=lc&1;
    for (int n=0;n<4;n++){
      C acc{0,0};
      #pragma unroll
      for (int m3=0;m3<2;m3++)
      #pragma unroll
      for (int m1=0;m1<2;m1++){
        C g2 = G[8+n]  [(p3*2+p1)*4 + (m3*2+m1)];
        C ga = G[2*n]  [(m3*2+p2)*4 + (l3*2+l2)];
        C gb = G[2*n+1][(m1*2+p0)*4 + (l1*2+l0)];
        acc = cfma(g2, cmul(ga, gb), acc);
      }
      sV[n*256 + lp*16 + lc] = acc;
    }
  }
  if (tid < 64) {                 // T_n(s) = A_{4n}(t0) A(t1) A(t2) A/Chat(t3)
    int n = tid >> 4, s = tid & 15;
    int t0 = (s>>3)&1;
    C u0 = uL[(4*n)*4 + t0*2 + 0], u1 = uL[(4*n)*4 + t0*2 + 1];
    C P00=u0, P01=u0, P10=u1, P11={-u1.x,-u1.y};
    #pragma unroll
    for (int i=1;i<4;i++){
      int t = (s >> (3-i)) & 1;
      int q = 4*n + i;
      C v0 = uL[q*4 + t*2 + 0], v1 = uL[q*4 + t*2 + 1];
      C b00, b01, b10, b11;
      if (n == 3 && i == 3) { b00=v0; b01={0,0}; b10=v1; b11={0,0}; }   // Chat
      else { b00=v0; b01=v0; b10=v1; b11={-v1.x,-v1.y}; }               // A-form
      C n00 = cfma(P01, b10, cmul(P00, b00));
      C n01 = cfma(P01, b11, cmul(P00, b01));
      C n10 = cfma(P11, b10, cmul(P10, b00));
      C n11 = cfma(P11, b11, cmul(P10, b01));
      P00=n00; P01=n01; P10=n10; P11=n11;
    }
    int base = tid << 2;          // [n][s][a][b]
    sT[base+0]=P00; sT[base+1]=P01; sT[base+2]=P10; sT[base+3]=P11;
  }
  __syncthreads();

  // ------- Phase C: M_n(s)[a,b] = sum_{s'} V_n[s,s'] T_n(s')[a,b] -----------
  {
    int n = tid >> 6, s = (tid >> 2) & 15, ab = tid & 3;
    const C* vr = &sV[n*256 + s*16];
    const C* tn = &sT[(n<<6) + ab];
    C acc{0,0};
    #pragma unroll
    for (int k=0;k<16;k++) acc = cfma(vr[k], tn[k<<2], acc);
    sM[tid] = acc;
  }
  __syncthreads();

  // ------- Phase D: doubled transfers D_n^{+,Z} ------------------------------
  if (tid < 64) {
    int n = tid >> 4, p = tid & 15;
    int a=(p>>3)&1, a2=(p>>2)&1, bb=(p>>1)&1, b2=p&1;
    const C* mn = &sM[n<<6];
    C Slo{0,0}, Shi{0,0};
    #pragma unroll
    for (int s=0;s<8;s++)  Slo = cfmac(mn[(s<<2)+(a<<1)+bb], mn[(s<<2)+(a2<<1)+b2], Slo);
    #pragma unroll
    for (int s=8;s<16;s++) Shi = cfmac(mn[(s<<2)+(a<<1)+bb], mn[(s<<2)+(a2<<1)+b2], Shi);
    sDp[tid] = Slo + Shi;
    sDz[tid] = Slo - Shi;
  }
  __syncthreads();

  // ------- Phase E: contract 4 outputs ---------------------------------------
  if (tid < 4) {
    int o = tid;
    C v0={1,0}, v1={1,0}, v2={1,0}, v3={1,0};
    #pragma unroll
    for (int n=0;n<3;n++){
      const C* D = (n==o) ? &sDz[n<<4] : &sDp[n<<4];
      C n0{0,0}, n1{0,0}, n2{0,0}, n3{0,0};
      n0 = cfma(v0, D[ 0], n0); n0 = cfma(v1, D[ 4], n0); n0 = cfma(v2, D[ 8], n0); n0 = cfma(v3, D[12], n0);
      n1 = cfma(v0, D[ 1], n1); n1 = cfma(v1, D[ 5], n1); n1 = cfma(v2, D[ 9], n1); n1 = cfma(v3, D[13], n1);
      n2 = cfma(v0, D[ 2], n2); n2 = cfma(v1, D[ 6], n2); n2 = cfma(v2, D[10], n2); n2 = cfma(v3, D[14], n2);
      n3 = cfma(v0, D[ 3], n3); n3 = cfma(v1, D[ 7], n3); n3 = cfma(v2, D[11], n3); n3 = cfma(v3, D[15], n3);
      v0=n0; v1=n1; v2=n2; v3=n3;
    }
    const C* D3 = (o==3) ? &sDz[3<<4] : &sDp[3<<4];
    C e{0,0};                       // column (b,b') = (0,0)
    e = cfma(v0, D3[ 0], e); e = cfma(v1, D3[ 4], e);
    e = cfma(v2, D3[ 8], e); e = cfma(v3, D3[12], e);
    qv[o] = e.x * (1.0f/65536.0f);
  }
  __syncthreads();

  // ------- Phase F: linear head ----------------------------------------------
  if (tid < 9) {
    float acc = bias[tid];
    #pragma unroll
    for (int k=0;k<4;k++) acc = fmaf(qv[k], Wm[tid*4+k], acc);
    outp[b*9 + tid] = acc;
  }
}

// -----------------------------------------------------------------------------
extern "C" void kernel_launch(void* const* d_in, const int* in_sizes, int n_in,
                              void* d_out, int out_size, void* d_ws, size_t ws_size,
                              hipStream_t stream)
{
  (void)in_sizes; (void)n_in; (void)out_size; (void)d_ws; (void)ws_size;
  const float* x    = (const float*)d_in[0];   // [32][16]
  const float* w    = (const float*)d_in[1];   // [78]
  const float* Wm   = (const float*)d_in[2];   // [9][4]
  const float* bias = (const float*)d_in[3];   // [9]
  float* outp = (float*)d_out;                 // [32][9]

  qk_all<<<32, 256, 0, stream>>>(x, w, Wm, bias, outp);
}